// Round 1
// baseline (700.430 us; speedup 1.0000x reference)
//
#include <hip/hip_runtime.h>
#include <hip/hip_bf16.h>

#define T_TOKENS 65536
#define EMBED 256
#define DOWN 64
#define NE 10
#define TILE 64
#define XS_STRIDE 260   // 256 + 4 pad: breaks bank aliasing for 4-row b128 reads
#define HS_STRIDE 68    // 64 + 4 pad

// ---------------- Kernel 1: gating (logits, top-2, softmax, expert lists, importance) ----------------
__global__ __launch_bounds__(256) void gating_kernel(
    const float* __restrict__ x, const float* __restrict__ wg,
    int* __restrict__ counts, float* __restrict__ importance,
    int* __restrict__ tok_list, float* __restrict__ gate_list)
{
    __shared__ int lcount[NE];
    __shared__ float limp[NE];
    __shared__ int gbase[NE];
    int tid = threadIdx.x;
    if (tid < NE) { lcount[tid] = 0; limp[tid] = 0.f; }
    __syncthreads();

    int t = blockIdx.x * 256 + tid;
    float acc[NE];
#pragma unroll
    for (int e = 0; e < NE; e++) acc[e] = 0.f;
    const float4* x4 = (const float4*)(x + (size_t)t * EMBED);
    for (int d4 = 0; d4 < EMBED / 4; d4++) {
        float4 xv = x4[d4];
        const float* xs = (const float*)&xv;
#pragma unroll
        for (int j = 0; j < 4; j++) {
            int d = d4 * 4 + j;
#pragma unroll
            for (int e = 0; e < NE; e++)
                acc[e] = fmaf(xs[j], wg[d * NE + e], acc[e]);   // uniform addr -> s_load
        }
    }
    // top-2, first-occurrence wins on ties (matches lax.top_k)
    float l0 = -INFINITY, l1 = -INFINITY;
    int i0 = 0, i1 = 0;
#pragma unroll
    for (int e = 0; e < NE; e++) {
        float v = acc[e];
        if (v > l0) { l1 = l0; i1 = i0; l0 = v; i0 = e; }
        else if (v > l1) { l1 = v; i1 = e; }
    }
    float ex = __expf(l1 - l0);
    float g0 = 1.f / (1.f + ex);
    float g1 = ex * g0;

    int lp0 = atomicAdd(&lcount[i0], 1);
    int lp1 = atomicAdd(&lcount[i1], 1);
    atomicAdd(&limp[i0], g0);
    atomicAdd(&limp[i1], g1);
    __syncthreads();
    if (tid < NE) {
        gbase[tid] = atomicAdd(&counts[tid], lcount[tid]);   // 10 atomics/block only
        atomicAdd(&importance[tid], limp[tid]);
    }
    __syncthreads();
    int p0 = gbase[i0] + lp0;
    int p1 = gbase[i1] + lp1;
    tok_list[i0 * T_TOKENS + p0] = t;
    gate_list[i0 * T_TOKENS + p0] = g0;
    tok_list[i1 * T_TOKENS + p1] = t;
    gate_list[i1 * T_TOKENS + p1] = g1;
}

// ---------------- Kernel 2: per-expert FFN over compacted token tiles ----------------
__global__ __launch_bounds__(256) void expert_kernel(
    const float* __restrict__ x,
    const float* __restrict__ w1, const float* __restrict__ b1,
    const float* __restrict__ w2, const float* __restrict__ b2,
    const int* __restrict__ counts,
    const int* __restrict__ tok_list, const float* __restrict__ gate_list,
    float* __restrict__ out)
{
    int e = blockIdx.y;
    int cnt = counts[e];
    int start = blockIdx.x * TILE;
    if (start >= cnt) return;
    int m = min(TILE, cnt - start);

    __shared__ __align__(16) float Xs[TILE * XS_STRIDE];  // 66.6 KB; reused for H -> 2 blocks/CU
    __shared__ int toks[TILE];
    __shared__ float gval[TILE];
    int tid = threadIdx.x;
    if (tid < TILE) {
        int v = 0; float g = 0.f;
        if (tid < m) {
            v = tok_list[e * T_TOKENS + start + tid];
            g = gate_list[e * T_TOKENS + start + tid];
        }
        toks[tid] = v; gval[tid] = g;
    }
    __syncthreads();
    // stage X (gather rows; zero-fill beyond m so full-tile GEMM is safe)
    {
        int r = tid >> 6;
        int c4 = (tid & 63) << 2;
#pragma unroll
        for (int p = 0; p < 16; p++, r += 4) {
            float4 v = make_float4(0.f, 0.f, 0.f, 0.f);
            if (r < m) v = *(const float4*)(x + (size_t)toks[r] * EMBED + c4);
            *(float4*)&Xs[r * XS_STRIDE + c4] = v;
        }
    }
    __syncthreads();
    // GEMM1: H[64][64] = relu(X @ w1[e] + b1[e]); thread = 4x4 tile
    int ct = tid & 15, rt = tid >> 4;
    int c0 = ct * 4, r0 = rt * 4;
    float acc1[4][4];
#pragma unroll
    for (int i = 0; i < 4; i++)
#pragma unroll
        for (int j = 0; j < 4; j++) acc1[i][j] = 0.f;
    const float* w1e = w1 + (size_t)e * EMBED * DOWN;
    for (int k = 0; k < EMBED; k += 4) {
        float4 xr[4], wr[4];
#pragma unroll
        for (int i = 0; i < 4; i++) xr[i] = *(const float4*)&Xs[(r0 + i) * XS_STRIDE + k];
#pragma unroll
        for (int kk = 0; kk < 4; kk++) wr[kk] = *(const float4*)(w1e + (k + kk) * DOWN + c0);
#pragma unroll
        for (int kk = 0; kk < 4; kk++)
#pragma unroll
            for (int i = 0; i < 4; i++)
#pragma unroll
                for (int j = 0; j < 4; j++)
                    acc1[i][j] = fmaf(((const float*)&xr[i])[kk], ((const float*)&wr[kk])[j], acc1[i][j]);
    }
    __syncthreads();   // all Xs reads done before overwrite
    {
        float4 b1v = *(const float4*)(b1 + e * DOWN + c0);
#pragma unroll
        for (int i = 0; i < 4; i++)
#pragma unroll
            for (int j = 0; j < 4; j++) {
                float h = acc1[i][j] + ((const float*)&b1v)[j];
                Xs[(r0 + i) * HS_STRIDE + (c0 + j)] = fmaxf(h, 0.f);  // H lives in Xs region
            }
    }
    __syncthreads();
    // GEMM2: Y[64][256] = H @ w2[e] + b2[e]; scatter g*Y into out via atomics
    int ct2 = tid & 63, rt2 = tid >> 6;
    int cc0 = ct2 * 4;
    const float* w2e = w2 + (size_t)e * DOWN * EMBED;
    float4 b2v = *(const float4*)(b2 + e * EMBED + cc0);
#pragma unroll
    for (int rr = 0; rr < 4; rr++) {
        int rbase = rr * 16 + rt2 * 4;
        float acc2[4][4];
#pragma unroll
        for (int i = 0; i < 4; i++)
#pragma unroll
            for (int j = 0; j < 4; j++) acc2[i][j] = 0.f;
        for (int k = 0; k < DOWN; k += 4) {
            float4 hr[4], wr[4];
#pragma unroll
            for (int i = 0; i < 4; i++) hr[i] = *(const float4*)&Xs[(rbase + i) * HS_STRIDE + k];
#pragma unroll
            for (int kk = 0; kk < 4; kk++) wr[kk] = *(const float4*)(w2e + (k + kk) * EMBED + cc0);
#pragma unroll
            for (int kk = 0; kk < 4; kk++)
#pragma unroll
                for (int i = 0; i < 4; i++)
#pragma unroll
                    for (int j = 0; j < 4; j++)
                        acc2[i][j] = fmaf(((const float*)&hr[i])[kk], ((const float*)&wr[kk])[j], acc2[i][j]);
        }
#pragma unroll
        for (int i = 0; i < 4; i++) {
            int r = rbase + i;
            if (r < m) {
                float g = gval[r];
                float* op = out + (size_t)toks[r] * EMBED + cc0;
#pragma unroll
                for (int j = 0; j < 4; j++)
                    atomicAdd(op + j, g * (acc2[i][j] + ((const float*)&b2v)[j]));
            }
        }
    }
}

// ---------------- Kernel 3: scale by 0.5 in place + |y| partial sums ----------------
__global__ __launch_bounds__(256) void finalize_kernel(float* __restrict__ out, float* __restrict__ kdpart)
{
    size_t idx = (size_t)blockIdx.x * 256 + threadIdx.x;
    float4 v = ((const float4*)out)[idx];
    float s = fabsf(v.x) + fabsf(v.y) + fabsf(v.z) + fabsf(v.w);
    v.x *= 0.5f; v.y *= 0.5f; v.z *= 0.5f; v.w *= 0.5f;
    ((float4*)out)[idx] = v;
#pragma unroll
    for (int o = 32; o > 0; o >>= 1) s += __shfl_down(s, o, 64);
    __shared__ float red[4];
    int lane = threadIdx.x & 63, wid = threadIdx.x >> 6;
    if (lane == 0) red[wid] = s;
    __syncthreads();
    if (threadIdx.x == 0) {
        float tot = red[0] + red[1] + red[2] + red[3];
        atomicAdd(&kdpart[blockIdx.x & 63], tot);   // 64-way spread: ~256 atomics/address
    }
}

// ---------------- Kernel 4: aux CV loss + kd loss -> d_out[T*D] ----------------
__global__ void loss_kernel(const int* __restrict__ counts, const float* __restrict__ importance,
                            const float* __restrict__ kdpart, float* __restrict__ loss_out)
{
    if (threadIdx.x == 0) {
        float kd = 0.f;
        for (int i = 0; i < 64; i++) kd += kdpart[i];
        kd *= (1.f / (float)((size_t)T_TOKENS * EMBED));
        float mi = 0.f, ml = 0.f;
        for (int e = 0; e < NE; e++) { mi += importance[e]; ml += (float)counts[e]; }
        mi *= (1.f / NE); ml *= (1.f / NE);
        float vi = 0.f, vl = 0.f;
        for (int e = 0; e < NE; e++) {
            float di = importance[e] - mi; vi += di * di;
            float dl = (float)counts[e] - ml; vl += dl * dl;
        }
        vi *= (1.f / (NE - 1)); vl *= (1.f / (NE - 1));   // unbiased (ddof=1)
        float aux = vi / (mi * mi + 1e-10f) + vl / (ml * ml + 1e-10f);
        loss_out[0] = aux + kd;
    }
}

extern "C" void kernel_launch(void* const* d_in, const int* in_sizes, int n_in,
                              void* d_out, int out_size, void* d_ws, size_t ws_size,
                              hipStream_t stream)
{
    (void)in_sizes; (void)n_in; (void)out_size; (void)ws_size;
    const float* x  = (const float*)d_in[0];
    const float* wg = (const float*)d_in[1];
    const float* w1 = (const float*)d_in[2];
    const float* b1 = (const float*)d_in[3];
    const float* w2 = (const float*)d_in[4];
    const float* b2 = (const float*)d_in[5];
    float* out = (float*)d_out;

    char* ws = (char*)d_ws;
    int*   counts     = (int*)ws;             // 16 ints (load == counts: softmax gates > 0)
    float* importance = (float*)(ws + 64);    // 16 floats
    float* kdpart     = (float*)(ws + 128);   // 64 floats
    int*   tok_list   = (int*)(ws + 512);                                     // 10*65536 ints
    float* gate_list  = (float*)(ws + 512 + (size_t)NE * T_TOKENS * sizeof(int)); // 10*65536 floats

    hipMemsetAsync(ws, 0, 512, stream);
    hipMemsetAsync(out, 0, (size_t)T_TOKENS * EMBED * sizeof(float), stream);

    gating_kernel<<<T_TOKENS / 256, 256, 0, stream>>>(x, wg, counts, importance, tok_list, gate_list);
    expert_kernel<<<dim3(T_TOKENS / TILE, NE), 256, 0, stream>>>(x, w1, b1, w2, b2, counts, tok_list, gate_list, out);
    finalize_kernel<<<(T_TOKENS * (EMBED / 4)) / 256, 256, 0, stream>>>(out, kdpart);
    loss_kernel<<<1, 64, 0, stream>>>(counts, importance, kdpart, out + (size_t)T_TOKENS * EMBED);
}

// Round 2
// 395.468 us; speedup vs baseline: 1.7711x; 1.7711x over previous
//
#include <hip/hip_runtime.h>
#include <hip/hip_bf16.h>

#define T_TOKENS 65536
#define EMBED 256
#define DOWN 64
#define NE 10
#define TILE 64
#define XS_STRIDE 260   // 256 + 4 pad: breaks bank aliasing for 4-row b128 reads
#define HS_STRIDE 68    // 64 + 4 pad

// ---------------- Kernel 1: gating (logits, top-2, softmax, expert lists w/ slot bit, importance) ----
__global__ __launch_bounds__(256) void gating_kernel(
    const float* __restrict__ x, const float* __restrict__ wg,
    int* __restrict__ counts, float* __restrict__ importance,
    int* __restrict__ tok_list, float* __restrict__ gate_list)
{
    __shared__ int lcount[NE];
    __shared__ float limp[NE];
    __shared__ int gbase[NE];
    int tid = threadIdx.x;
    if (tid < NE) { lcount[tid] = 0; limp[tid] = 0.f; }
    __syncthreads();

    int t = blockIdx.x * 256 + tid;
    float acc[NE];
#pragma unroll
    for (int e = 0; e < NE; e++) acc[e] = 0.f;
    const float4* x4 = (const float4*)(x + (size_t)t * EMBED);
    for (int d4 = 0; d4 < EMBED / 4; d4++) {
        float4 xv = x4[d4];
        const float* xs = (const float*)&xv;
#pragma unroll
        for (int j = 0; j < 4; j++) {
            int d = d4 * 4 + j;
#pragma unroll
            for (int e = 0; e < NE; e++)
                acc[e] = fmaf(xs[j], wg[d * NE + e], acc[e]);   // uniform addr -> s_load
        }
    }
    // top-2, first-occurrence wins on ties (matches lax.top_k)
    float l0 = -INFINITY, l1 = -INFINITY;
    int i0 = 0, i1 = 0;
#pragma unroll
    for (int e = 0; e < NE; e++) {
        float v = acc[e];
        if (v > l0) { l1 = l0; i1 = i0; l0 = v; i0 = e; }
        else if (v > l1) { l1 = v; i1 = e; }
    }
    float ex = __expf(l1 - l0);
    float g0 = 1.f / (1.f + ex);
    float g1 = ex * g0;

    int lp0 = atomicAdd(&lcount[i0], 1);
    int lp1 = atomicAdd(&lcount[i1], 1);
    atomicAdd(&limp[i0], g0);
    atomicAdd(&limp[i1], g1);
    __syncthreads();
    if (tid < NE) {
        gbase[tid] = atomicAdd(&counts[tid], lcount[tid]);   // 10 global atomics/block only
        atomicAdd(&importance[tid], limp[tid]);
    }
    __syncthreads();
    int p0 = gbase[i0] + lp0;
    int p1 = gbase[i1] + lp1;
    tok_list[i0 * T_TOKENS + p0] = (t << 1) | 0;   // packed: token<<1 | slot
    gate_list[i0 * T_TOKENS + p0] = g0;
    tok_list[i1 * T_TOKENS + p1] = (t << 1) | 1;
    gate_list[i1 * T_TOKENS + p1] = g1;
}

// ---------------- Kernel 2: per-expert FFN; plain stores to slot0->out, slot1->ybuf1 ----------------
__global__ __launch_bounds__(256) void expert_kernel(
    const float* __restrict__ x,
    const float* __restrict__ w1, const float* __restrict__ b1,
    const float* __restrict__ w2, const float* __restrict__ b2,
    const int* __restrict__ counts,
    const int* __restrict__ tok_list, const float* __restrict__ gate_list,
    float* __restrict__ y0buf, float* __restrict__ y1buf)
{
    int e = blockIdx.y;
    int cnt = counts[e];
    int start = blockIdx.x * TILE;
    if (start >= cnt) return;
    int m = min(TILE, cnt - start);

    __shared__ __align__(16) float Xs[TILE * XS_STRIDE];  // 66.6 KB; reused for H -> 2 blocks/CU
    __shared__ int toks[TILE];    // packed (token<<1)|slot
    __shared__ float gval[TILE];
    int tid = threadIdx.x;
    if (tid < TILE) {
        int v = 0; float g = 0.f;
        if (tid < m) {
            v = tok_list[e * T_TOKENS + start + tid];
            g = gate_list[e * T_TOKENS + start + tid];
        }
        toks[tid] = v; gval[tid] = g;
    }
    __syncthreads();
    // stage X (gather rows; zero-fill beyond m so full-tile GEMM is safe)
    {
        int r = tid >> 6;
        int c4 = (tid & 63) << 2;
#pragma unroll
        for (int p = 0; p < 16; p++, r += 4) {
            float4 v = make_float4(0.f, 0.f, 0.f, 0.f);
            if (r < m) v = *(const float4*)(x + (size_t)(toks[r] >> 1) * EMBED + c4);
            *(float4*)&Xs[r * XS_STRIDE + c4] = v;
        }
    }
    __syncthreads();
    // GEMM1: H[64][64] = relu(X @ w1[e] + b1[e]); thread = 4x4 tile
    int ct = tid & 15, rt = tid >> 4;
    int c0 = ct * 4, r0 = rt * 4;
    float acc1[4][4];
#pragma unroll
    for (int i = 0; i < 4; i++)
#pragma unroll
        for (int j = 0; j < 4; j++) acc1[i][j] = 0.f;
    const float* w1e = w1 + (size_t)e * EMBED * DOWN;
    for (int k = 0; k < EMBED; k += 4) {
        float4 xr[4], wr[4];
#pragma unroll
        for (int i = 0; i < 4; i++) xr[i] = *(const float4*)&Xs[(r0 + i) * XS_STRIDE + k];
#pragma unroll
        for (int kk = 0; kk < 4; kk++) wr[kk] = *(const float4*)(w1e + (k + kk) * DOWN + c0);
#pragma unroll
        for (int kk = 0; kk < 4; kk++)
#pragma unroll
            for (int i = 0; i < 4; i++)
#pragma unroll
                for (int j = 0; j < 4; j++)
                    acc1[i][j] = fmaf(((const float*)&xr[i])[kk], ((const float*)&wr[kk])[j], acc1[i][j]);
    }
    __syncthreads();   // all Xs reads done before overwrite
    {
        float4 b1v = *(const float4*)(b1 + e * DOWN + c0);
#pragma unroll
        for (int i = 0; i < 4; i++)
#pragma unroll
            for (int j = 0; j < 4; j++) {
                float h = acc1[i][j] + ((const float*)&b1v)[j];
                Xs[(r0 + i) * HS_STRIDE + (c0 + j)] = fmaxf(h, 0.f);  // H lives in Xs region
            }
    }
    __syncthreads();
    // GEMM2: Y[64][256] = H @ w2[e] + b2[e]; plain gated stores, coalesced per row
    int ct2 = tid & 63, rt2 = tid >> 6;
    int cc0 = ct2 * 4;
    const float* w2e = w2 + (size_t)e * DOWN * EMBED;
    float4 b2v = *(const float4*)(b2 + e * EMBED + cc0);
#pragma unroll
    for (int rr = 0; rr < 4; rr++) {
        int rbase = rr * 16 + rt2 * 4;
        float acc2[4][4];
#pragma unroll
        for (int i = 0; i < 4; i++)
#pragma unroll
            for (int j = 0; j < 4; j++) acc2[i][j] = 0.f;
        for (int k = 0; k < DOWN; k += 4) {
            float4 hr[4], wr[4];
#pragma unroll
            for (int i = 0; i < 4; i++) hr[i] = *(const float4*)&Xs[(rbase + i) * HS_STRIDE + k];
#pragma unroll
            for (int kk = 0; kk < 4; kk++) wr[kk] = *(const float4*)(w2e + (k + kk) * EMBED + cc0);
#pragma unroll
            for (int kk = 0; kk < 4; kk++)
#pragma unroll
                for (int i = 0; i < 4; i++)
#pragma unroll
                    for (int j = 0; j < 4; j++)
                        acc2[i][j] = fmaf(((const float*)&hr[i])[kk], ((const float*)&wr[kk])[j], acc2[i][j]);
        }
#pragma unroll
        for (int i = 0; i < 4; i++) {
            int r = rbase + i;
            if (r < m) {
                int packed = toks[r];
                float g = gval[r];
                float* dst = ((packed & 1) ? y1buf : y0buf) + (size_t)(packed >> 1) * EMBED + cc0;
                float4 v;
                v.x = g * (acc2[i][0] + b2v.x);
                v.y = g * (acc2[i][1] + b2v.y);
                v.z = g * (acc2[i][2] + b2v.z);
                v.w = g * (acc2[i][3] + b2v.w);
                *(float4*)dst = v;
            }
        }
    }
}

// ---------------- Kernel 3: combine slots + scale + |y| partial sums ----------------
__global__ __launch_bounds__(256) void combine_kernel(
    float* __restrict__ out, const float* __restrict__ y1buf, float* __restrict__ kdpart)
{
    size_t idx = (size_t)blockIdx.x * 256 + threadIdx.x;
    float4 a = ((const float4*)out)[idx];
    float4 b = ((const float4*)y1buf)[idx];
    float4 v;
    v.x = a.x + b.x; v.y = a.y + b.y; v.z = a.z + b.z; v.w = a.w + b.w;
    float s = fabsf(v.x) + fabsf(v.y) + fabsf(v.z) + fabsf(v.w);
    v.x *= 0.5f; v.y *= 0.5f; v.z *= 0.5f; v.w *= 0.5f;
    ((float4*)out)[idx] = v;
#pragma unroll
    for (int o = 32; o > 0; o >>= 1) s += __shfl_down(s, o, 64);
    __shared__ float red[4];
    int lane = threadIdx.x & 63, wid = threadIdx.x >> 6;
    if (lane == 0) red[wid] = s;
    __syncthreads();
    if (threadIdx.x == 0) {
        float tot = red[0] + red[1] + red[2] + red[3];
        atomicAdd(&kdpart[blockIdx.x & 63], tot);   // 64-way spread: ~256 atomics/address
    }
}

// ---------------- Kernel 4: aux CV loss + kd loss -> d_out[T*D] ----------------
__global__ void loss_kernel(const int* __restrict__ counts, const float* __restrict__ importance,
                            const float* __restrict__ kdpart, float* __restrict__ loss_out)
{
    if (threadIdx.x == 0) {
        float kd = 0.f;
        for (int i = 0; i < 64; i++) kd += kdpart[i];
        kd *= (1.f / (float)((size_t)T_TOKENS * EMBED));
        float mi = 0.f, ml = 0.f;
        for (int e = 0; e < NE; e++) { mi += importance[e]; ml += (float)counts[e]; }
        mi *= (1.f / NE); ml *= (1.f / NE);
        float vi = 0.f, vl = 0.f;
        for (int e = 0; e < NE; e++) {
            float di = importance[e] - mi; vi += di * di;
            float dl = (float)counts[e] - ml; vl += dl * dl;
        }
        vi *= (1.f / (NE - 1)); vl *= (1.f / (NE - 1));   // unbiased (ddof=1)
        float aux = vi / (mi * mi + 1e-10f) + vl / (ml * ml + 1e-10f);
        loss_out[0] = aux + kd;
    }
}

extern "C" void kernel_launch(void* const* d_in, const int* in_sizes, int n_in,
                              void* d_out, int out_size, void* d_ws, size_t ws_size,
                              hipStream_t stream)
{
    (void)in_sizes; (void)n_in; (void)out_size; (void)ws_size;
    const float* x  = (const float*)d_in[0];
    const float* wg = (const float*)d_in[1];
    const float* w1 = (const float*)d_in[2];
    const float* b1 = (const float*)d_in[3];
    const float* w2 = (const float*)d_in[4];
    const float* b2 = (const float*)d_in[5];
    float* out = (float*)d_out;

    char* ws = (char*)d_ws;
    int*   counts     = (int*)ws;             // 16 ints (load == counts: softmax gates > 0)
    float* importance = (float*)(ws + 64);    // 16 floats
    float* kdpart     = (float*)(ws + 128);   // 64 floats
    int*   tok_list   = (int*)(ws + 512);                                         // 10*65536 ints
    float* gate_list  = (float*)(ws + 512 + (size_t)NE * T_TOKENS * sizeof(int)); // 10*65536 floats
    float* y1buf      = (float*)(ws + 512 + (size_t)NE * T_TOKENS * 8);           // 65536*256 floats (67 MB)

    hipMemsetAsync(ws, 0, 512, stream);   // counts + importance + kdpart only; out needs no zeroing now

    gating_kernel<<<T_TOKENS / 256, 256, 0, stream>>>(x, wg, counts, importance, tok_list, gate_list);
    expert_kernel<<<dim3(T_TOKENS / TILE, NE), 256, 0, stream>>>(x, w1, b1, w2, b2, counts, tok_list, gate_list, out, y1buf);
    combine_kernel<<<(T_TOKENS * (EMBED / 4)) / 256, 256, 0, stream>>>(out, y1buf, kdpart);
    loss_kernel<<<1, 64, 0, stream>>>(counts, importance, kdpart, out + (size_t)T_TOKENS * EMBED);
}

// Round 3
// 264.578 us; speedup vs baseline: 2.6474x; 1.4947x over previous
//
#include <hip/hip_runtime.h>
#include <hip/hip_bf16.h>

#define T_TOKENS 65536
#define EMBED 256
#define DOWN 64
#define NE 10
#define TILE 64
#define XROW 72   // 64 + 8 bf16 pad: b128 frag reads land 8-per-bank (min phases)

typedef __attribute__((ext_vector_type(8))) short short8;   // 8 bf16 = 4 VGPRs (MFMA A/B frag)
typedef __attribute__((ext_vector_type(4))) float f32x4;    // MFMA C/D frag

__device__ inline unsigned short f2bf(float f) {            // RNE float->bf16
    unsigned u = __builtin_bit_cast(unsigned, f);
    u += 0x7fff + ((u >> 16) & 1);
    return (unsigned short)(u >> 16);
}
__device__ inline float bf2f(unsigned short h) {
    unsigned u = ((unsigned)h) << 16;
    return __builtin_bit_cast(float, u);
}

// ---------------- Kernel 0: pack w1/w2 into MFMA B-fragment order, split hi/lo bf16 --------------
// B-frag layout (16x16x32): n = lane&15, k = (lane>>4)*8 + j, j=0..8 contiguous in memory.
__global__ __launch_bounds__(256) void pack_kernel(
    const float* __restrict__ w1, const float* __restrict__ w2,
    unsigned short* __restrict__ w1ph, unsigned short* __restrict__ w1pl,
    unsigned short* __restrict__ w2ph, unsigned short* __restrict__ w2pl)
{
    int gid = blockIdx.x * 256 + threadIdx.x;
    int lane = gid & 63;
    int fid = gid >> 6;
    int n16 = lane & 15;
    int kbase = ((lane >> 4) & 3) * 8;
    if (fid < 320) {            // w1 frag-blocks: fid = (e*4 + ct)*8 + kb   (K=256 -> 8 kb)
        int kb = fid & 7, ect = fid >> 3;
        int ct = ect & 3, e = ect >> 2;
        int n = ct * 16 + n16;
        int k0 = kb * 32 + kbase;
#pragma unroll
        for (int j = 0; j < 8; ++j) {
            float v = w1[((size_t)e * EMBED + k0 + j) * DOWN + n];
            unsigned short h = f2bf(v);
            w1ph[(size_t)fid * 512 + lane * 8 + j] = h;
            w1pl[(size_t)fid * 512 + lane * 8 + j] = f2bf(v - bf2f(h));
        }
    } else if (fid < 640) {     // w2 frag-blocks: f2 = (e*16 + ct)*2 + kb  (K=64 -> 2 kb)
        int f2 = fid - 320;
        int kb = f2 & 1, ect = f2 >> 1;
        int ct = ect & 15, e = ect >> 4;
        int n = ct * 16 + n16;
        int k0 = kb * 32 + kbase;
#pragma unroll
        for (int j = 0; j < 8; ++j) {
            float v = w2[((size_t)e * DOWN + k0 + j) * EMBED + n];
            unsigned short h = f2bf(v);
            w2ph[(size_t)f2 * 512 + lane * 8 + j] = h;
            w2pl[(size_t)f2 * 512 + lane * 8 + j] = f2bf(v - bf2f(h));
        }
    }
}

// ---------------- Kernel 1: gating (fp32, unchanged: top-k flips are not tolerable in bf16) -----
__global__ __launch_bounds__(256) void gating_kernel(
    const float* __restrict__ x, const float* __restrict__ wg,
    int* __restrict__ counts, float* __restrict__ importance,
    int* __restrict__ tok_list, float* __restrict__ gate_list)
{
    __shared__ int lcount[NE];
    __shared__ float limp[NE];
    __shared__ int gbase[NE];
    int tid = threadIdx.x;
    if (tid < NE) { lcount[tid] = 0; limp[tid] = 0.f; }
    __syncthreads();

    int t = blockIdx.x * 256 + tid;
    float acc[NE];
#pragma unroll
    for (int e = 0; e < NE; e++) acc[e] = 0.f;
    const float4* x4 = (const float4*)(x + (size_t)t * EMBED);
    for (int d4 = 0; d4 < EMBED / 4; d4++) {
        float4 xv = x4[d4];
        const float* xs = (const float*)&xv;
#pragma unroll
        for (int j = 0; j < 4; j++) {
            int d = d4 * 4 + j;
#pragma unroll
            for (int e = 0; e < NE; e++)
                acc[e] = fmaf(xs[j], wg[d * NE + e], acc[e]);
        }
    }
    float l0 = -INFINITY, l1 = -INFINITY;
    int i0 = 0, i1 = 0;
#pragma unroll
    for (int e = 0; e < NE; e++) {
        float v = acc[e];
        if (v > l0) { l1 = l0; i1 = i0; l0 = v; i0 = e; }
        else if (v > l1) { l1 = v; i1 = e; }
    }
    float ex = __expf(l1 - l0);
    float g0 = 1.f / (1.f + ex);
    float g1 = ex * g0;

    int lp0 = atomicAdd(&lcount[i0], 1);
    int lp1 = atomicAdd(&lcount[i1], 1);
    atomicAdd(&limp[i0], g0);
    atomicAdd(&limp[i1], g1);
    __syncthreads();
    if (tid < NE) {
        gbase[tid] = atomicAdd(&counts[tid], lcount[tid]);
        atomicAdd(&importance[tid], limp[tid]);
    }
    __syncthreads();
    int p0 = gbase[i0] + lp0;
    int p1 = gbase[i1] + lp1;
    tok_list[i0 * T_TOKENS + p0] = (t << 1) | 0;   // token<<1 | slot
    gate_list[i0 * T_TOKENS + p0] = g0;
    tok_list[i1 * T_TOKENS + p1] = (t << 1) | 1;
    gate_list[i1 * T_TOKENS + p1] = g1;
}

// ---------------- Kernel 2: MFMA expert FFN (split-bf16, 3-term) --------------------------------
__global__ __launch_bounds__(256, 4) void expert_kernel(
    const float* __restrict__ x,
    const unsigned short* __restrict__ w1ph, const unsigned short* __restrict__ w1pl,
    const unsigned short* __restrict__ w2ph, const unsigned short* __restrict__ w2pl,
    const float* __restrict__ b1, const float* __restrict__ b2,
    const int* __restrict__ counts,
    const int* __restrict__ tok_list, const float* __restrict__ gate_list,
    float* __restrict__ y0, float* __restrict__ y1)
{
    int e = blockIdx.y;
    int cnt = counts[e];
    int start = blockIdx.x * TILE;
    if (start >= cnt) return;
    int m = min(TILE, cnt - start);

    __shared__ __align__(16) unsigned short Xh[TILE * XROW];  // 9216 B each
    __shared__ __align__(16) unsigned short Xl[TILE * XROW];
    __shared__ __align__(16) unsigned short Hh[TILE * XROW];
    __shared__ __align__(16) unsigned short Hl[TILE * XROW];
    __shared__ int toks[TILE];
    __shared__ float gval[TILE];
    // total 37.4 KB -> 4 blocks/CU

    int tid = threadIdx.x;
    if (tid < TILE) {
        int v = 0; float g = 0.f;
        if (tid < m) {
            v = tok_list[e * T_TOKENS + start + tid];
            g = gate_list[e * T_TOKENS + start + tid];
        }
        toks[tid] = v; gval[tid] = g;
    }
    __syncthreads();

    int lane = tid & 63;
    int wv = tid >> 6;          // wave 0..3
    int ln15 = lane & 15;
    int quad = lane >> 4;

    // staging decode: thread -> (row, 4 float4s)
    int srow = tid >> 2;
    int scol0 = (tid & 3) * 16;
    bool srow_ok = srow < m;
    const float* xrow = x + (size_t)(toks[srow] >> 1) * EMBED;

    // GEMM1: C1[64 tok][64 down]; wave wv owns col-tile ct=wv, all 4 row-tiles.
    f32x4 acc1[4];
#pragma unroll
    for (int rt = 0; rt < 4; ++rt) acc1[rt] = (f32x4){0.f, 0.f, 0.f, 0.f};

    const unsigned short* w1he = w1ph + (((size_t)e * 4 + wv) * 8) * 512;
    const unsigned short* w1le = w1pl + (((size_t)e * 4 + wv) * 8) * 512;

    for (int c = 0; c < 4; ++c) {           // K chunks of 64
        // stage X chunk, split hi/lo
#pragma unroll
        for (int p = 0; p < 4; ++p) {
            int col = scol0 + p * 4;
            float4 v = make_float4(0.f, 0.f, 0.f, 0.f);
            if (srow_ok) v = *(const float4*)(xrow + c * 64 + col);
            const float* vs = (const float*)&v;
            ushort4 hv, lv;
            unsigned short* hp = (unsigned short*)&hv;
            unsigned short* lp = (unsigned short*)&lv;
#pragma unroll
            for (int i = 0; i < 4; ++i) {
                unsigned short h = f2bf(vs[i]);
                hp[i] = h;
                lp[i] = f2bf(vs[i] - bf2f(h));
            }
            *(ushort4*)&Xh[srow * XROW + col] = hv;
            *(ushort4*)&Xl[srow * XROW + col] = lv;
        }
        __syncthreads();
#pragma unroll
        for (int kb = 0; kb < 2; ++kb) {
            int kbg = c * 2 + kb;
            short8 bh = *(const short8*)(w1he + (size_t)kbg * 512 + lane * 8);
            short8 bl = *(const short8*)(w1le + (size_t)kbg * 512 + lane * 8);
            int aoff = kb * 32 + quad * 8;
#pragma unroll
            for (int rt = 0; rt < 4; ++rt) {
                short8 ah = *(const short8*)&Xh[(rt * 16 + ln15) * XROW + aoff];
                short8 al = *(const short8*)&Xl[(rt * 16 + ln15) * XROW + aoff];
                acc1[rt] = __builtin_amdgcn_mfma_f32_16x16x32_bf16(ah, bh, acc1[rt], 0, 0, 0);
                acc1[rt] = __builtin_amdgcn_mfma_f32_16x16x32_bf16(ah, bl, acc1[rt], 0, 0, 0);
                acc1[rt] = __builtin_amdgcn_mfma_f32_16x16x32_bf16(al, bh, acc1[rt], 0, 0, 0);
            }
        }
        __syncthreads();
    }

    // epilogue GEMM1: bias + relu, split to H hi/lo in LDS (C/D: row=quad*4+reg, col=ln15)
    float b1v = b1[e * DOWN + wv * 16 + ln15];
#pragma unroll
    for (int rt = 0; rt < 4; ++rt) {
#pragma unroll
        for (int r = 0; r < 4; ++r) {
            float h = fmaxf(acc1[rt][r] + b1v, 0.f);
            unsigned short hh = f2bf(h);
            int row = rt * 16 + quad * 4 + r;
            Hh[row * XROW + wv * 16 + ln15] = hh;
            Hl[row * XROW + wv * 16 + ln15] = f2bf(h - bf2f(hh));
        }
    }
    __syncthreads();

    // GEMM2: C2[64 tok][256]; wave wv owns col-tiles 4wv..4wv+3, K=64 (2 kb)
    float b2v[4];
#pragma unroll
    for (int ci = 0; ci < 4; ++ci)
        b2v[ci] = b2[e * EMBED + (wv * 4 + ci) * 16 + ln15];

#pragma unroll
    for (int rt = 0; rt < 4; ++rt) {
        short8 ah[2], al[2];
#pragma unroll
        for (int kb = 0; kb < 2; ++kb) {
            int aoff = kb * 32 + quad * 8;
            ah[kb] = *(const short8*)&Hh[(rt * 16 + ln15) * XROW + aoff];
            al[kb] = *(const short8*)&Hl[(rt * 16 + ln15) * XROW + aoff];
        }
        int rowbase = rt * 16 + quad * 4;
#pragma unroll
        for (int ci = 0; ci < 4; ++ci) {
            int ct = wv * 4 + ci;
            const unsigned short* p2h = w2ph + (((size_t)e * 16 + ct) * 2) * 512;
            const unsigned short* p2l = w2pl + (((size_t)e * 16 + ct) * 2) * 512;
            f32x4 acc = (f32x4){0.f, 0.f, 0.f, 0.f};
#pragma unroll
            for (int kb = 0; kb < 2; ++kb) {
                short8 bh = *(const short8*)(p2h + kb * 512 + lane * 8);
                short8 bl = *(const short8*)(p2l + kb * 512 + lane * 8);
                acc = __builtin_amdgcn_mfma_f32_16x16x32_bf16(ah[kb], bh, acc, 0, 0, 0);
                acc = __builtin_amdgcn_mfma_f32_16x16x32_bf16(ah[kb], bl, acc, 0, 0, 0);
                acc = __builtin_amdgcn_mfma_f32_16x16x32_bf16(al[kb], bh, acc, 0, 0, 0);
            }
#pragma unroll
            for (int r = 0; r < 4; ++r) {
                int row = rowbase + r;
                if (row < m) {
                    int packed = toks[row];
                    float g = gval[row];
                    float val = g * (acc[r] + b2v[ci]);
                    float* dst = (packed & 1) ? y1 : y0;
                    dst[(size_t)(packed >> 1) * EMBED + ct * 16 + ln15] = val;
                }
            }
        }
    }
}

// ---------------- Kernel 3: combine slots + scale + |y| partial sums ----------------------------
__global__ __launch_bounds__(256) void combine_kernel(
    float* __restrict__ out, const float* __restrict__ y1buf, float* __restrict__ kdpart)
{
    size_t idx = (size_t)blockIdx.x * 256 + threadIdx.x;
    float4 a = ((const float4*)out)[idx];
    float4 b = ((const float4*)y1buf)[idx];
    float4 v;
    v.x = a.x + b.x; v.y = a.y + b.y; v.z = a.z + b.z; v.w = a.w + b.w;
    float s = fabsf(v.x) + fabsf(v.y) + fabsf(v.z) + fabsf(v.w);
    v.x *= 0.5f; v.y *= 0.5f; v.z *= 0.5f; v.w *= 0.5f;
    ((float4*)out)[idx] = v;
#pragma unroll
    for (int o = 32; o > 0; o >>= 1) s += __shfl_down(s, o, 64);
    __shared__ float red[4];
    int lane = threadIdx.x & 63, wid = threadIdx.x >> 6;
    if (lane == 0) red[wid] = s;
    __syncthreads();
    if (threadIdx.x == 0) {
        float tot = red[0] + red[1] + red[2] + red[3];
        atomicAdd(&kdpart[blockIdx.x & 63], tot);
    }
}

// ---------------- Kernel 4: aux CV loss + kd loss -----------------------------------------------
__global__ void loss_kernel(const int* __restrict__ counts, const float* __restrict__ importance,
                            const float* __restrict__ kdpart, float* __restrict__ loss_out)
{
    if (threadIdx.x == 0) {
        float kd = 0.f;
        for (int i = 0; i < 64; i++) kd += kdpart[i];
        kd *= (1.f / (float)((size_t)T_TOKENS * EMBED));
        float mi = 0.f, ml = 0.f;
        for (int e = 0; e < NE; e++) { mi += importance[e]; ml += (float)counts[e]; }
        mi *= (1.f / NE); ml *= (1.f / NE);
        float vi = 0.f, vl = 0.f;
        for (int e = 0; e < NE; e++) {
            float di = importance[e] - mi; vi += di * di;
            float dl = (float)counts[e] - ml; vl += dl * dl;
        }
        vi *= (1.f / (NE - 1)); vl *= (1.f / (NE - 1));
        float aux = vi / (mi * mi + 1e-10f) + vl / (ml * ml + 1e-10f);
        loss_out[0] = aux + kd;
    }
}

extern "C" void kernel_launch(void* const* d_in, const int* in_sizes, int n_in,
                              void* d_out, int out_size, void* d_ws, size_t ws_size,
                              hipStream_t stream)
{
    (void)in_sizes; (void)n_in; (void)out_size; (void)ws_size;
    const float* x  = (const float*)d_in[0];
    const float* wg = (const float*)d_in[1];
    const float* w1 = (const float*)d_in[2];
    const float* b1 = (const float*)d_in[3];
    const float* w2 = (const float*)d_in[4];
    const float* b2 = (const float*)d_in[5];
    float* out = (float*)d_out;

    char* ws = (char*)d_ws;
    int*   counts     = (int*)ws;                 // 16 ints
    float* importance = (float*)(ws + 64);        // 16 floats
    float* kdpart     = (float*)(ws + 128);       // 64 floats
    size_t off = 512;
    int*   tok_list   = (int*)(ws + off);   off += (size_t)NE * T_TOKENS * 4;   // 2.62 MB
    float* gate_list  = (float*)(ws + off); off += (size_t)NE * T_TOKENS * 4;   // 2.62 MB
    unsigned short* w1ph = (unsigned short*)(ws + off); off += 327680;
    unsigned short* w1pl = (unsigned short*)(ws + off); off += 327680;
    unsigned short* w2ph = (unsigned short*)(ws + off); off += 327680;
    unsigned short* w2pl = (unsigned short*)(ws + off); off += 327680;
    float* y1buf = (float*)(ws + off);            // 67.1 MB; total ~73.7 MB

    hipMemsetAsync(ws, 0, 512, stream);

    pack_kernel<<<160, 256, 0, stream>>>(w1, w2, w1ph, w1pl, w2ph, w2pl);
    gating_kernel<<<T_TOKENS / 256, 256, 0, stream>>>(x, wg, counts, importance, tok_list, gate_list);
    expert_kernel<<<dim3(T_TOKENS / TILE, NE), 256, 0, stream>>>(
        x, w1ph, w1pl, w2ph, w2pl, b1, b2, counts, tok_list, gate_list, out, y1buf);
    combine_kernel<<<(T_TOKENS * (EMBED / 4)) / 256, 256, 0, stream>>>(out, y1buf, kdpart);
    loss_kernel<<<1, 64, 0, stream>>>(counts, importance, kdpart, out + (size_t)T_TOKENS * EMBED);
}

// Round 4
// 260.990 us; speedup vs baseline: 2.6837x; 1.0137x over previous
//
#include <hip/hip_runtime.h>
#include <hip/hip_bf16.h>

#define T_TOKENS 65536
#define EMBED 256
#define DOWN 64
#define NE 10
#define NPAIR 100          // ordered (e0,e1) buckets, e0=top1
#define MAXQ 1280          // >= 1024 + 90 tiles
#define XROW 72            // 64 + 8 bf16 pad; 144 B row stride keeps b128 16B-aligned

typedef __attribute__((ext_vector_type(8))) short short8;   // 8 bf16 (MFMA A/B frag)
typedef __attribute__((ext_vector_type(4))) float f32x4;    // MFMA C/D frag

__device__ inline unsigned short f2bf(float f) {            // RNE float->bf16
    unsigned u = __builtin_bit_cast(unsigned, f);
    u += 0x7fff + ((u >> 16) & 1);
    return (unsigned short)(u >> 16);
}
__device__ inline float bf2f(unsigned short h) {
    unsigned u = ((unsigned)h) << 16;
    return __builtin_bit_cast(float, u);
}

// ---------------- Kernel 0: pack w1/w2 into MFMA B-frag order, split hi/lo bf16 ------------------
__global__ __launch_bounds__(256) void pack_kernel(
    const float* __restrict__ w1, const float* __restrict__ w2,
    unsigned short* __restrict__ w1ph, unsigned short* __restrict__ w1pl,
    unsigned short* __restrict__ w2ph, unsigned short* __restrict__ w2pl)
{
    int gid = blockIdx.x * 256 + threadIdx.x;
    int lane = gid & 63;
    int fid = gid >> 6;
    int n16 = lane & 15;
    int kbase = ((lane >> 4) & 3) * 8;
    if (fid < 320) {            // w1: fid = (e*4 + ct)*8 + kb
        int kb = fid & 7, ect = fid >> 3;
        int ct = ect & 3, e = ect >> 2;
        int n = ct * 16 + n16;
        int k0 = kb * 32 + kbase;
#pragma unroll
        for (int j = 0; j < 8; ++j) {
            float v = w1[((size_t)e * EMBED + k0 + j) * DOWN + n];
            unsigned short h = f2bf(v);
            w1ph[(size_t)fid * 512 + lane * 8 + j] = h;
            w1pl[(size_t)fid * 512 + lane * 8 + j] = f2bf(v - bf2f(h));
        }
    } else if (fid < 640) {     // w2: f2 = (e*16 + ct)*2 + kb
        int f2 = fid - 320;
        int kb = f2 & 1, ect = f2 >> 1;
        int ct = ect & 15, e = ect >> 4;
        int n = ct * 16 + n16;
        int k0 = kb * 32 + kbase;
#pragma unroll
        for (int j = 0; j < 8; ++j) {
            float v = w2[((size_t)e * DOWN + k0 + j) * EMBED + n];
            unsigned short h = f2bf(v);
            w2ph[(size_t)f2 * 512 + lane * 8 + j] = h;
            w2pl[(size_t)f2 * 512 + lane * 8 + j] = f2bf(v - bf2f(h));
        }
    }
}

// ---------------- Kernel 1: gating, coalesced via double-buffered LDS; pair buckets --------------
__global__ __launch_bounds__(256) void gating_kernel(
    const float* __restrict__ x, const float* __restrict__ wg,
    int* __restrict__ pcount, float* __restrict__ importance,
    int* __restrict__ btok, float* __restrict__ bg0)
{
    __shared__ float Xs[2][256 * 33];    // stride 33: compute reads (tid+c)%32 conflict-free
    __shared__ int lcount[NPAIR];
    __shared__ int gbase[NPAIR];
    __shared__ float limp[16];
    int tid = threadIdx.x;
    if (tid < NPAIR) lcount[tid] = 0;
    if (tid < 16) limp[tid] = 0.f;

    int tokbase = blockIdx.x * 256;
    const float4* x4 = (const float4*)x;
    int rbase = tid >> 3, c4 = tid & 7;   // 8 rows x 8 float4: 128B segments per row

    float4 pre[8];
#pragma unroll
    for (int i = 0; i < 8; ++i)
        pre[i] = x4[(size_t)(tokbase + i * 32 + rbase) * 64 + c4];

    float acc[NE];
#pragma unroll
    for (int e = 0; e < NE; e++) acc[e] = 0.f;

    for (int cc = 0; cc < 8; ++cc) {
        float* buf = Xs[cc & 1];
#pragma unroll
        for (int i = 0; i < 8; ++i) {
            float* d = &buf[(i * 32 + rbase) * 33 + c4 * 4];
            d[0] = pre[i].x; d[1] = pre[i].y; d[2] = pre[i].z; d[3] = pre[i].w;
        }
        if (cc < 7) {
#pragma unroll
            for (int i = 0; i < 8; ++i)
                pre[i] = x4[(size_t)(tokbase + i * 32 + rbase) * 64 + (cc + 1) * 8 + c4];
        }
        __syncthreads();   // single barrier/chunk: buffer alternation protects reuse
        const float* wgc = wg + cc * 32 * NE;   // wave-uniform -> scalar loads
#pragma unroll
        for (int c = 0; c < 32; ++c) {
            float xv = buf[tid * 33 + c];
#pragma unroll
            for (int e = 0; e < NE; ++e)
                acc[e] = fmaf(xv, wgc[c * NE + e], acc[e]);
        }
    }

    // top-2 (first occurrence wins ties, matches lax.top_k)
    float l0 = -INFINITY, l1 = -INFINITY;
    int i0 = 0, i1 = 0;
#pragma unroll
    for (int e = 0; e < NE; e++) {
        float v = acc[e];
        if (v > l0) { l1 = l0; i1 = i0; l0 = v; i0 = e; }
        else if (v > l1) { l1 = v; i1 = e; }
    }
    float ex = __expf(l1 - l0);
    float g0 = 1.f / (1.f + ex);

    int p = i0 * NE + i1;
    int lp = atomicAdd(&lcount[p], 1);
    atomicAdd(&limp[i0], g0);
    atomicAdd(&limp[i1], 1.f - g0);
    __syncthreads();
    if (tid < NPAIR) {
        int c = lcount[tid];
        gbase[tid] = c ? atomicAdd(&pcount[tid], c) : 0;
    }
    if (tid < NE) atomicAdd(&importance[tid], limp[tid]);
    __syncthreads();
    int pos = gbase[p] + lp;
    btok[p * T_TOKENS + pos] = tokbase + tid;
    bg0[p * T_TOKENS + pos] = g0;
}

// ---------------- Kernel 2: build tile work-queue --------------------------------------------------
__global__ void queue_kernel(const int* __restrict__ pcount,
                             int* __restrict__ qp, int* __restrict__ qs, int* __restrict__ nq)
{
    if (threadIdx.x == 0) {
        int n = 0;
        for (int p = 0; p < NPAIR; p++) {
            int c = pcount[p];
            for (int s = 0; s < c; s += 64) { qp[n] = p; qs[n] = s; n++; }
        }
        *nq = n;
    }
}

// ---------------- Kernel 3: fused pair-FFN: both experts, final combine+scale+KD -----------------
__global__ __launch_bounds__(256, 3) void expert_kernel(
    const float* __restrict__ x,
    const unsigned short* __restrict__ w1ph, const unsigned short* __restrict__ w1pl,
    const unsigned short* __restrict__ w2ph, const unsigned short* __restrict__ w2pl,
    const float* __restrict__ b1, const float* __restrict__ b2,
    const int* __restrict__ pcount, const int* __restrict__ qp, const int* __restrict__ qs,
    const int* __restrict__ nq,
    const int* __restrict__ btok, const float* __restrict__ bg0,
    float* __restrict__ out, float* __restrict__ kdpart)
{
    int bid = blockIdx.x;
    if (bid >= *nq) return;
    int p = qp[bid], s = qs[bid];
    int e0 = p / NE, e1 = p - e0 * NE;
    int m = min(64, pcount[p] - s);

    __shared__ __align__(16) unsigned short Xh[64 * XROW], Xl[64 * XROW];  // 18.4 KB
    __shared__ __align__(16) unsigned short H0h[4096], H0l[4096];          // frag-order: 8 KB each
    __shared__ __align__(16) unsigned short H1h[4096], H1l[4096];          // total H: 32 KB
    __shared__ int toks[64];
    __shared__ float gv0s[64], gv1s[64];
    __shared__ float kdw[4];

    int tid = threadIdx.x;
    if (tid < 64) {
        int v = 0; float g = 0.f;
        if (tid < m) {
            v = btok[p * T_TOKENS + s + tid];
            g = bg0[p * T_TOKENS + s + tid];
        }
        toks[tid] = v;
        gv0s[tid] = g;
        gv1s[tid] = (tid < m) ? (1.f - g) : 0.f;
    }
    __syncthreads();

    int lane = tid & 63, wv = tid >> 6;
    int ln15 = lane & 15, quad = lane >> 4;
    int srow = tid >> 2, sc0 = (tid & 3) * 16;
    const float* xrow = x + (size_t)toks[srow] * EMBED;
    bool srow_ok = srow < m;

    f32x4 a10[4], a11[4];
#pragma unroll
    for (int rt = 0; rt < 4; ++rt) { a10[rt] = (f32x4){0,0,0,0}; a11[rt] = (f32x4){0,0,0,0}; }

    const unsigned short* w1h0 = w1ph + (((size_t)e0 * 4 + wv) * 8) * 512;
    const unsigned short* w1l0 = w1pl + (((size_t)e0 * 4 + wv) * 8) * 512;
    const unsigned short* w1h1 = w1ph + (((size_t)e1 * 4 + wv) * 8) * 512;
    const unsigned short* w1l1 = w1pl + (((size_t)e1 * 4 + wv) * 8) * 512;

    for (int cc = 0; cc < 4; ++cc) {                 // K chunks of 64
#pragma unroll
        for (int p4 = 0; p4 < 4; ++p4) {
            int col = sc0 + p4 * 4;
            float4 v = make_float4(0.f, 0.f, 0.f, 0.f);
            if (srow_ok) v = *(const float4*)(xrow + cc * 64 + col);
            const float* vs = (const float*)&v;
            ushort4 hv, lv;
            unsigned short* hp = (unsigned short*)&hv;
            unsigned short* lp2 = (unsigned short*)&lv;
#pragma unroll
            for (int i = 0; i < 4; ++i) {
                unsigned short h = f2bf(vs[i]);
                hp[i] = h;
                lp2[i] = f2bf(vs[i] - bf2f(h));
            }
            *(ushort4*)&Xh[srow * XROW + col] = hv;
            *(ushort4*)&Xl[srow * XROW + col] = lv;
        }
        __syncthreads();
#pragma unroll
        for (int kb = 0; kb < 2; ++kb) {
            int kbg = cc * 2 + kb;
            short8 bh0 = *(const short8*)(w1h0 + (size_t)kbg * 512 + lane * 8);
            short8 bl0 = *(const short8*)(w1l0 + (size_t)kbg * 512 + lane * 8);
            short8 bh1 = *(const short8*)(w1h1 + (size_t)kbg * 512 + lane * 8);
            short8 bl1 = *(const short8*)(w1l1 + (size_t)kbg * 512 + lane * 8);
            int aoff = kb * 32 + quad * 8;
#pragma unroll
            for (int rt = 0; rt < 4; ++rt) {
                short8 ah = *(const short8*)&Xh[(rt * 16 + ln15) * XROW + aoff];
                short8 al = *(const short8*)&Xl[(rt * 16 + ln15) * XROW + aoff];
                a10[rt] = __builtin_amdgcn_mfma_f32_16x16x32_bf16(ah, bh0, a10[rt], 0, 0, 0);
                a10[rt] = __builtin_amdgcn_mfma_f32_16x16x32_bf16(ah, bl0, a10[rt], 0, 0, 0);
                a10[rt] = __builtin_amdgcn_mfma_f32_16x16x32_bf16(al, bh0, a10[rt], 0, 0, 0);
                a11[rt] = __builtin_amdgcn_mfma_f32_16x16x32_bf16(ah, bh1, a11[rt], 0, 0, 0);
                a11[rt] = __builtin_amdgcn_mfma_f32_16x16x32_bf16(ah, bl1, a11[rt], 0, 0, 0);
                a11[rt] = __builtin_amdgcn_mfma_f32_16x16x32_bf16(al, bh1, a11[rt], 0, 0, 0);
            }
        }
        __syncthreads();
    }

    // H epilogue: bias+relu, pre-scale by gates, write in A-frag order:
    // element (m,k) of tile (rt,kb) lives at lane'=(k>>3)*16+m, j=k&7.
    // producer col = wv*16+ln15 -> kb=wv>>1, lane'=((wv&1)*2+(ln15>>3))*16+quad*4+r, j=ln15&7.
    {
        float b1v0 = b1[e0 * DOWN + wv * 16 + ln15];
        float b1v1 = b1[e1 * DOWN + wv * 16 + ln15];
        int kbH = wv >> 1;
        int laneH = (((wv & 1) * 2 + (ln15 >> 3)) * 16) + quad * 4;
        int jH = ln15 & 7;
#pragma unroll
        for (int rt = 0; rt < 4; ++rt) {
#pragma unroll
            for (int r = 0; r < 4; ++r) {
                int row = rt * 16 + quad * 4 + r;
                float g0 = gv0s[row], g1 = gv1s[row];
                float h0 = fmaxf(a10[rt][r] + b1v0, 0.f) * g0;
                float h1 = fmaxf(a11[rt][r] + b1v1, 0.f) * g1;
                int idx = ((rt * 2 + kbH) * 64 + laneH + r) * 8 + jH;
                unsigned short h0h = f2bf(h0);
                unsigned short h1h = f2bf(h1);
                H0h[idx] = h0h; H0l[idx] = f2bf(h0 - bf2f(h0h));
                H1h[idx] = h1h; H1l[idx] = f2bf(h1 - bf2f(h1h));
            }
        }
    }
    __syncthreads();

    // GEMM2: y = (g0 h0) w2_e0 + (g1 h1) w2_e1; epilogue adds gated biases, KD, 0.5 scale
    float b20[4], b21[4];
#pragma unroll
    for (int ci = 0; ci < 4; ++ci) {
        b20[ci] = b2[e0 * EMBED + (wv * 4 + ci) * 16 + ln15];
        b21[ci] = b2[e1 * EMBED + (wv * 4 + ci) * 16 + ln15];
    }
    float kdacc = 0.f;
#pragma unroll
    for (int rt = 0; rt < 4; ++rt) {
        short8 ah0[2], al0[2], ah1[2], al1[2];
#pragma unroll
        for (int kb = 0; kb < 2; ++kb) {
            int base = ((rt * 2 + kb) * 64 + lane) * 8;   // contiguous 16B/lane
            ah0[kb] = *(const short8*)&H0h[base];
            al0[kb] = *(const short8*)&H0l[base];
            ah1[kb] = *(const short8*)&H1h[base];
            al1[kb] = *(const short8*)&H1l[base];
        }
        int rowb = rt * 16 + quad * 4;
        float gr0[4], gr1[4];
#pragma unroll
        for (int r = 0; r < 4; ++r) { gr0[r] = gv0s[rowb + r]; gr1[r] = gv1s[rowb + r]; }
#pragma unroll
        for (int ci = 0; ci < 4; ++ci) {
            int ct = wv * 4 + ci;
            const unsigned short* p0h = w2ph + (((size_t)e0 * 16 + ct) * 2) * 512;
            const unsigned short* p0l = w2pl + (((size_t)e0 * 16 + ct) * 2) * 512;
            const unsigned short* p1h = w2ph + (((size_t)e1 * 16 + ct) * 2) * 512;
            const unsigned short* p1l = w2pl + (((size_t)e1 * 16 + ct) * 2) * 512;
            f32x4 acc = (f32x4){0, 0, 0, 0};
#pragma unroll
            for (int kb = 0; kb < 2; ++kb) {
                short8 bh = *(const short8*)(p0h + kb * 512 + lane * 8);
                short8 bl = *(const short8*)(p0l + kb * 512 + lane * 8);
                acc = __builtin_amdgcn_mfma_f32_16x16x32_bf16(ah0[kb], bh, acc, 0, 0, 0);
                acc = __builtin_amdgcn_mfma_f32_16x16x32_bf16(ah0[kb], bl, acc, 0, 0, 0);
                acc = __builtin_amdgcn_mfma_f32_16x16x32_bf16(al0[kb], bh, acc, 0, 0, 0);
                short8 ch = *(const short8*)(p1h + kb * 512 + lane * 8);
                short8 cl = *(const short8*)(p1l + kb * 512 + lane * 8);
                acc = __builtin_amdgcn_mfma_f32_16x16x32_bf16(ah1[kb], ch, acc, 0, 0, 0);
                acc = __builtin_amdgcn_mfma_f32_16x16x32_bf16(ah1[kb], cl, acc, 0, 0, 0);
                acc = __builtin_amdgcn_mfma_f32_16x16x32_bf16(al1[kb], ch, acc, 0, 0, 0);
            }
#pragma unroll
            for (int r = 0; r < 4; ++r) {
                int row = rowb + r;
                float val = acc[r] + gr0[r] * b20[ci] + gr1[r] * b21[ci];  // unscaled y
                if (row < m) {
                    kdacc += fabsf(val);
                    out[(size_t)toks[row] * EMBED + ct * 16 + ln15] = 0.5f * val;
                }
            }
        }
    }
    // KD block reduction
#pragma unroll
    for (int o = 32; o > 0; o >>= 1) kdacc += __shfl_down(kdacc, o, 64);
    if (lane == 0) kdw[wv] = kdacc;
    __syncthreads();
    if (tid == 0)
        atomicAdd(&kdpart[bid & 63], kdw[0] + kdw[1] + kdw[2] + kdw[3]);
}

// ---------------- Kernel 4: aux CV loss + kd loss -------------------------------------------------
__global__ void loss_kernel(const int* __restrict__ pcount, const float* __restrict__ importance,
                            const float* __restrict__ kdpart, float* __restrict__ loss_out)
{
    if (threadIdx.x == 0) {
        float kd = 0.f;
        for (int i = 0; i < 64; i++) kd += kdpart[i];
        kd *= (1.f / (float)((size_t)T_TOKENS * EMBED));
        float load[NE];
        for (int e = 0; e < NE; e++) load[e] = 0.f;
        for (int p = 0; p < NPAIR; p++) {
            float c = (float)pcount[p];
            load[p / NE] += c;
            load[p % NE] += c;
        }
        float mi = 0.f, ml = 0.f;
        for (int e = 0; e < NE; e++) { mi += importance[e]; ml += load[e]; }
        mi *= (1.f / NE); ml *= (1.f / NE);
        float vi = 0.f, vl = 0.f;
        for (int e = 0; e < NE; e++) {
            float di = importance[e] - mi; vi += di * di;
            float dl = load[e] - ml; vl += dl * dl;
        }
        vi *= (1.f / (NE - 1)); vl *= (1.f / (NE - 1));   // ddof=1
        float aux = vi / (mi * mi + 1e-10f) + vl / (ml * ml + 1e-10f);
        loss_out[0] = aux + kd;
    }
}

extern "C" void kernel_launch(void* const* d_in, const int* in_sizes, int n_in,
                              void* d_out, int out_size, void* d_ws, size_t ws_size,
                              hipStream_t stream)
{
    (void)in_sizes; (void)n_in; (void)out_size; (void)ws_size;
    const float* x  = (const float*)d_in[0];
    const float* wg = (const float*)d_in[1];
    const float* w1 = (const float*)d_in[2];
    const float* b1 = (const float*)d_in[3];
    const float* w2 = (const float*)d_in[4];
    const float* b2 = (const float*)d_in[5];
    float* out = (float*)d_out;

    char* ws = (char*)d_ws;
    int*   pcount     = (int*)ws;                  // 128 ints (100 used)
    float* importance = (float*)(ws + 512);        // 16 floats
    float* kdpart     = (float*)(ws + 576);        // 64 floats
    int*   nq         = (int*)(ws + 832);
    int*   qp         = (int*)(ws + 1024);         // MAXQ ints
    int*   qs         = (int*)(ws + 1024 + MAXQ * 4);
    size_t off = 16384;
    int*   btok = (int*)(ws + off);    off += (size_t)NPAIR * T_TOKENS * 4;   // 26.2 MB
    float* bg0  = (float*)(ws + off);  off += (size_t)NPAIR * T_TOKENS * 4;   // 26.2 MB
    unsigned short* w1ph = (unsigned short*)(ws + off); off += 327680;
    unsigned short* w1pl = (unsigned short*)(ws + off); off += 327680;
    unsigned short* w2ph = (unsigned short*)(ws + off); off += 327680;
    unsigned short* w2pl = (unsigned short*)(ws + off); off += 327680;      // ~53.8 MB total

    hipMemsetAsync(ws, 0, 1024, stream);   // pcount + importance + kdpart + nq

    pack_kernel<<<160, 256, 0, stream>>>(w1, w2, w1ph, w1pl, w2ph, w2pl);
    gating_kernel<<<T_TOKENS / 256, 256, 0, stream>>>(x, wg, pcount, importance, btok, bg0);
    queue_kernel<<<1, 64, 0, stream>>>(pcount, qp, qs, nq);
    expert_kernel<<<1114, 256, 0, stream>>>(
        x, w1ph, w1pl, w2ph, w2pl, b1, b2, pcount, qp, qs, nq, btok, bg0, out, kdpart);
    loss_kernel<<<1, 64, 0, stream>>>(pcount, importance, kdpart, out + (size_t)T_TOKENS * EMBED);
}